// Round 1
// 502.490 us; speedup vs baseline: 1.0038x; 1.0038x over previous
//
#include <hip/hip_runtime.h>

// SwinTransformerBlock: B=8, H=W=256, C=48, NH=3, WS=8, SS=4, N=64, HID=192
// fp32 in/out; all GEMMs bf16 MFMA 16x16x32 with "transposed D" (D=[feat][token])
// so epilogues write 4 consecutive features per lane (packed b64 / float4 RMW).

typedef short bfrag __attribute__((ext_vector_type(8)));   // 8 bf16 (4 VGPRs)
typedef float f32x4 __attribute__((ext_vector_type(4)));

__device__ __forceinline__ unsigned cvtpk(float lo, float hi) {
    unsigned r;
    asm("v_cvt_pk_bf16_f32 %0, %1, %2" : "=v"(r) : "v"(lo), "v"(hi));
    return r;   // low16 = bf16(lo), high16 = bf16(hi), RNE
}
__device__ __forceinline__ unsigned short f2bf(float f) {
    return (unsigned short)cvtpk(f, f);
}
__device__ __forceinline__ unsigned pk2(float a, float b) {
    return cvtpk(a, b);
}
__device__ __forceinline__ void bf2x(unsigned u, float& lo, float& hi) {
    union { unsigned i; float f; } a, b;
    a.i = u << 16; b.i = u & 0xffff0000u;
    lo = a.f; hi = b.f;
}

// ---------------- kernel 0: prep bf16 weights in d_ws ----------------
// u16 layout: w1p[192][64] | w2p[48][192] | qkvw[144][64] (q rows x0.25) | projw[48][64]
// then f32 qkvb[144] (q part x0.25)
#define WS_W1   0
#define WS_W2   12288
#define WS_QKVW 21504
#define WS_PROJ 30720
#define WS_QKVB 33792   // f32 from here (u16 offset)
__global__ __launch_bounds__(256) void prep_weights(
    const float* __restrict__ fc1_w, const float* __restrict__ fc2_w,
    const float* __restrict__ qkv_w, const float* __restrict__ qkv_b,
    const float* __restrict__ proj_w,
    unsigned short* __restrict__ ws)
{
    int idx = blockIdx.x * 256 + threadIdx.x;
    if (idx < 12288) {                       // fc1 [192][48] -> [192][64]
        int o = idx >> 6, k = idx & 63;
        ws[WS_W1 + idx] = (k < 48) ? f2bf(fc1_w[o * 48 + k]) : 0;
    } else if (idx < 21504) {                // fc2 [48][192] as-is
        int j = idx - 12288;
        ws[WS_W2 + j] = f2bf(fc2_w[j]);
    } else if (idx < 30720) {                // qkv [144][48] -> [144][64], q x0.25
        int j = idx - 21504;
        int n = j >> 6, k = j & 63;
        float v = (k < 48) ? qkv_w[n * 48 + k] : 0.f;
        if (n < 48) v *= 0.25f;
        ws[WS_QKVW + j] = f2bf(v);
    } else if (idx < 33792) {                // proj [48][48] -> [48][64]
        int j = idx - 30720;
        int n = j >> 6, k = j & 63;
        ws[WS_PROJ + j] = (k < 48) ? f2bf(proj_w[n * 48 + k]) : 0;
    } else if (idx < 33792 + 144) {
        int j = idx - 33792;
        float* bb = reinterpret_cast<float*>(ws + WS_QKVB);
        bb[j] = qkv_b[j] * (j < 48 ? 0.25f : 1.f);
    }
}

// ---------------- kernel 1: per-window block ----------------
__global__ __launch_bounds__(256, 3) void win_kernel(
    const float* __restrict__ x,
    const float* __restrict__ gamma1,
    const float* __restrict__ beta1,
    const unsigned short* __restrict__ wsb,
    const float* __restrict__ rpb_t,
    const float* __restrict__ wf,
    const float* __restrict__ se_w1,
    const float* __restrict__ se_b1,
    const float* __restrict__ se_w2,
    const float* __restrict__ se_b2,
    const float* __restrict__ proj_b,
    float* __restrict__ out)
{
    __shared__ __align__(16) unsigned short xw[64][56];   // LN'd tokens [tok][ch]
    __shared__ __align__(16) unsigned short Qh[64][56];   // [tok][head*16+d]
    __shared__ __align__(16) unsigned short Kh[64][56];
    __shared__ __align__(16) unsigned short ao[64][56];   // attn out + SE [tok][ch]
    __shared__ __align__(16) unsigned short vT[48][72];   // [feat][tok]
    __shared__ __align__(16) unsigned short Pw[4][16][72];// per-wave P [query][key]
    __shared__ __align__(16) unsigned short zbuf[32];     // shared zero fragment
    __shared__ float rpb_s[675];
    __shared__ float se_c[48], se_buf[48];
    __shared__ int   gidx[64];

    const int tid = threadIdx.x;
    const int blk = blockIdx.x;
    const int bb = blk >> 10;
    const int wi = (blk >> 5) & 31;
    const int wj = blk & 31;

    const int w = tid >> 6;       // wave
    const int l = tid & 63;
    const int m = l & 15;
    const int q = l >> 4;
    const int q4 = q * 4;

    for (int i = tid; i < 675; i += 256) rpb_s[i] = rpb_t[i];
    if (tid < 32) zbuf[tid] = 0;

    // ---- LN1 + shifted gather: thread = (token, quarter) ----
    const int t = tid >> 2, part = tid & 3;
    {
        const int ti = t >> 3, tj = t & 7;
        const int si = wi * 8 + ti, sj = wj * 8 + tj;
        const int oi = (si + 4) & 255, oj = (sj + 4) & 255;
        const int g = (bb << 16) + (oi << 8) + oj;
        if (part == 0) gidx[t] = g;
        const float4* p4 = reinterpret_cast<const float4*>(x + (size_t)g * 48 + part * 12);
        float4 vr0 = p4[0], vr1 = p4[1], vr2 = p4[2];
        float s = vr0.x + vr0.y + vr0.z + vr0.w + vr1.x + vr1.y + vr1.z + vr1.w
                + vr2.x + vr2.y + vr2.z + vr2.w;
        float ss = vr0.x*vr0.x + vr0.y*vr0.y + vr0.z*vr0.z + vr0.w*vr0.w
                 + vr1.x*vr1.x + vr1.y*vr1.y + vr1.z*vr1.z + vr1.w*vr1.w
                 + vr2.x*vr2.x + vr2.y*vr2.y + vr2.z*vr2.z + vr2.w*vr2.w;
        s  += __shfl_xor(s, 1);  s  += __shfl_xor(s, 2);
        ss += __shfl_xor(ss, 1); ss += __shfl_xor(ss, 2);
        const float mu = s * (1.f / 48.f);
        const float var = ss * (1.f / 48.f) - mu * mu;
        const float rs = rsqrtf(var + 1e-5f);
        float vv[12];
        *reinterpret_cast<float4*>(vv + 0) = vr0;
        *reinterpret_cast<float4*>(vv + 4) = vr1;
        *reinterpret_cast<float4*>(vv + 8) = vr2;
        float ln[12];
        #pragma unroll
        for (int jj = 0; jj < 12; ++jj) {
            const int c = part * 12 + jj;
            ln[jj] = (vv[jj] - mu) * rs * gamma1[c] + beta1[c];
        }
        unsigned short* dst = &xw[t][part * 12];
        #pragma unroll
        for (int jj = 0; jj < 3; ++jj) {
            uint2 u; u.x = pk2(ln[jj*4+0], ln[jj*4+1]); u.y = pk2(ln[jj*4+2], ln[jj*4+3]);
            *reinterpret_cast<uint2*>(dst + jj * 4) = u;
        }
    }
    __syncthreads();

    // ---- qkv (waves 0-2, 12 tiles each) ; SE stage (wave 3) ----
    if (w < 3) {
        const float* qkvb = reinterpret_cast<const float*>(wsb + WS_QKVB);
        for (int tt = w; tt < 36; tt += 3) {
            const int ct = tt / 4, rt = tt & 3;
            bfrag B0 = *reinterpret_cast<const bfrag*>(&xw[rt * 16 + m][q * 8]);
            bfrag B1 = (q < 2) ? *reinterpret_cast<const bfrag*>(&xw[rt * 16 + m][32 + q * 8])
                               : *reinterpret_cast<const bfrag*>(&zbuf[(q - 2) * 8]);
            bfrag A0 = *reinterpret_cast<const bfrag*>(&wsb[WS_QKVW + (ct * 16 + m) * 64 + q * 8]);
            bfrag A1 = *reinterpret_cast<const bfrag*>(&wsb[WS_QKVW + (ct * 16 + m) * 64 + 32 + q * 8]);
            f32x4 d = {0.f, 0.f, 0.f, 0.f};
            d = __builtin_amdgcn_mfma_f32_16x16x32_bf16(A0, B0, d, 0, 0, 0);
            d = __builtin_amdgcn_mfma_f32_16x16x32_bf16(A1, B1, d, 0, 0, 0);
            const float4 bias = *reinterpret_cast<const float4*>(&qkvb[ct * 16 + q4]);
            float v0 = d[0] + bias.x, v1 = d[1] + bias.y, v2 = d[2] + bias.z, v3 = d[3] + bias.w;
            const int tk = rt * 16 + m;
            if (ct < 3) {
                uint2 u; u.x = pk2(v0, v1); u.y = pk2(v2, v3);
                *reinterpret_cast<uint2*>(&Qh[tk][ct * 16 + q4]) = u;
            } else if (ct < 6) {
                uint2 u; u.x = pk2(v0, v1); u.y = pk2(v2, v3);
                *reinterpret_cast<uint2*>(&Kh[tk][(ct - 3) * 16 + q4]) = u;
            } else {
                float vv4[4] = {v0, v1, v2, v3};
                #pragma unroll
                for (int ii = 0; ii < 4; ++ii) {
                    const int i = (ii + q) & 3;            // rotate rows -> 2-way banks
                    vT[(ct - 6) * 16 + q4 + i][tk] = f2bf(vv4[i]);
                }
            }
        }
    } else if (l < 48) {
        float s = 0.f;
        #pragma unroll 8
        for (int k = 0; k < 64; ++k) {
            union { unsigned i; float f; } u; u.i = ((unsigned)xw[k][l]) << 16;
            s += u.f;
        }
        se_c[l] = s * (1.f / 64.f);
    }
    if (w == 3) {
        __builtin_amdgcn_wave_barrier();
        if (l < 48) {
            float r1[3];
            #pragma unroll
            for (int r = 0; r < 3; ++r) {
                float s = se_b1[r];
                #pragma unroll 8
                for (int c = 0; c < 48; ++c) s += se_c[c] * se_w1[r * 48 + c];
                r1[r] = fmaxf(s, 0.f);
            }
            float s2 = se_b2[l];
            #pragma unroll
            for (int r = 0; r < 3; ++r) s2 += r1[r] * se_w2[l * 3 + r];
            se_buf[l] = wf[0] / (1.f + __expf(-s2));
        }
    }
    __syncthreads();

    // ---- fused attention: 3 slots per wave, no barriers (Pw wave-local) ----
    const bool masked_blk = (wi == 31) || (wj == 31);
    for (int j = 0; j < 3; ++j) {
        const int s = w * 3 + j;
        const int h = s >> 2, rt = s & 3;
        const int tq = rt * 16 + m;                 // query token (= D col)
        const int qi = tq >> 3, qj = tq & 7;
        const int rrq = (wi == 31) ? ((qi >= 4) ? 2 : 1) : 0;
        const int rcq = (wj == 31) ? ((qj >= 4) ? 2 : 1) : 0;
        bfrag Bq = (q < 2) ? *reinterpret_cast<const bfrag*>(&Qh[tq][h * 16 + q * 8])
                           : *reinterpret_cast<const bfrag*>(&zbuf[(q - 2) * 8]);
        float rtot = 0.f;
        #pragma unroll
        for (int ct = 0; ct < 4; ++ct) {
            bfrag Ak = (q < 2) ? *reinterpret_cast<const bfrag*>(&Kh[ct * 16 + m][h * 16 + q * 8])
                               : *reinterpret_cast<const bfrag*>(&zbuf[(q - 2) * 8]);
            f32x4 d = {0.f, 0.f, 0.f, 0.f};
            d = __builtin_amdgcn_mfma_f32_16x16x32_bf16(Ak, Bq, d, 0, 0, 0);
            float pv[4];
            #pragma unroll
            for (int i = 0; i < 4; ++i) {
                const int tk = ct * 16 + q4 + i;    // key token (= D row)
                const int ki = tk >> 3, kj = tk & 7;
                float sc = d[i] + rpb_s[((qi - ki + 7) * 15 + (qj - kj + 7)) * 3 + h];
                if (masked_blk) {
                    const int rrk = (wi == 31) ? ((ki >= 4) ? 2 : 1) : 0;
                    const int rck = (wj == 31) ? ((kj >= 4) ? 2 : 1) : 0;
                    if ((rrk != rrq) || (rck != rcq)) sc -= 100.f;
                }
                const float p = __expf(sc);
                rtot += p;
                pv[i] = p;
            }
            uint2 u; u.x = pk2(pv[0], pv[1]); u.y = pk2(pv[2], pv[3]);
            *reinterpret_cast<uint2*>(&Pw[w][m][ct * 16 + q4]) = u;
        }
        rtot += __shfl_xor(rtot, 16);
        rtot += __shfl_xor(rtot, 32);
        const float rinv = 1.f / rtot;
        // PV: D[vcol][query]
        bfrag Av0 = *reinterpret_cast<const bfrag*>(&vT[h * 16 + m][q * 8]);
        bfrag Av1 = *reinterpret_cast<const bfrag*>(&vT[h * 16 + m][32 + q * 8]);
        bfrag Bp0 = *reinterpret_cast<const bfrag*>(&Pw[w][m][q * 8]);
        bfrag Bp1 = *reinterpret_cast<const bfrag*>(&Pw[w][m][32 + q * 8]);
        f32x4 d = {0.f, 0.f, 0.f, 0.f};
        d = __builtin_amdgcn_mfma_f32_16x16x32_bf16(Av0, Bp0, d, 0, 0, 0);
        d = __builtin_amdgcn_mfma_f32_16x16x32_bf16(Av1, Bp1, d, 0, 0, 0);
        const int c0 = h * 16 + q4;
        const float4 sev = *reinterpret_cast<const float4*>(&se_buf[c0]);
        uint2 xv = *reinterpret_cast<const uint2*>(&xw[tq][c0]);
        float x0, x1, x2, x3;
        bf2x(xv.x, x0, x1); bf2x(xv.y, x2, x3);
        const float o0 = d[0] * rinv + sev.x * x0;
        const float o1 = d[1] * rinv + sev.y * x1;
        const float o2 = d[2] * rinv + sev.z * x2;
        const float o3 = d[3] * rinv + sev.w * x3;
        uint2 u; u.x = pk2(o0, o1); u.y = pk2(o2, o3);
        *reinterpret_cast<uint2*>(&ao[tq][c0]) = u;
    }
    __syncthreads();

    // ---- proj: D[out_ch][token] -> float4 RMW to out (window reverse via gidx) ----
    {
        bfrag B0 = *reinterpret_cast<const bfrag*>(&ao[w * 16 + m][q * 8]);
        bfrag B1 = (q < 2) ? *reinterpret_cast<const bfrag*>(&ao[w * 16 + m][32 + q * 8])
                           : *reinterpret_cast<const bfrag*>(&zbuf[(q - 2) * 8]);
        const int tok = w * 16 + m;
        const int g = gidx[tok];
        #pragma unroll
        for (int ct = 0; ct < 3; ++ct) {
            bfrag A0 = *reinterpret_cast<const bfrag*>(&wsb[WS_PROJ + (ct * 16 + m) * 64 + q * 8]);
            bfrag A1 = *reinterpret_cast<const bfrag*>(&wsb[WS_PROJ + (ct * 16 + m) * 64 + 32 + q * 8]);
            f32x4 d = {0.f, 0.f, 0.f, 0.f};
            d = __builtin_amdgcn_mfma_f32_16x16x32_bf16(A0, B0, d, 0, 0, 0);
            d = __builtin_amdgcn_mfma_f32_16x16x32_bf16(A1, B1, d, 0, 0, 0);
            const int c0 = ct * 16 + q4;
            const float4 bias = *reinterpret_cast<const float4*>(&proj_b[c0]);
            const float4 xr = *reinterpret_cast<const float4*>(&x[(size_t)g * 48 + c0]);
            float4 r;
            r.x = xr.x + d[0] + bias.x;
            r.y = xr.y + d[1] + bias.y;
            r.z = xr.z + d[2] + bias.z;
            r.w = xr.w + d[3] + bias.w;
            *reinterpret_cast<float4*>(&out[(size_t)g * 48 + c0]) = r;
        }
    }
}

// ---------------- kernel 2: MLP, fully wave-local (no barriers, no hB) ----------------
// LN thread map (t=tid>>2) puts tokens 16w..16w+15 in wave w — the same tokens wave w
// consumes in GEMM1/GEMM2. All LDS deps are wave-internal -> lgkmcnt only, no s_barrier.
// GEMM1 output (features at 4-granularity per lane) is re-granularized to the 8-wide
// B-fragment layout through a tiny per-wave ping-pong LDS scratch, one 32-k-tile at a time.
__global__ __launch_bounds__(256, 6) void mlp_mfma(
    float* __restrict__ xio,
    const float* __restrict__ gamma2,
    const float* __restrict__ beta2,
    const unsigned short* __restrict__ wsb,
    const float* __restrict__ fc1_b,
    const float* __restrict__ fc2_b)
{
    __shared__ __align__(16) unsigned short aB[64][72];      // LN'd [tok][ch]; ch 48..63 = 0
    __shared__ __align__(16) unsigned short sc[4][2][16][40];// per-wave exchange [wave][pp][tok][32f]
    const int tid = threadIdx.x;
    const size_t tok0 = (size_t)blockIdx.x * 64;

    // ---- LN2: thread = (token, quarter); wave-local rows of aB ----
    const int t = tid >> 2, part = tid & 3;
    {
        const float4* p4 = reinterpret_cast<const float4*>(xio + (tok0 + t) * 48 + part * 12);
        float4 vr0 = p4[0], vr1 = p4[1], vr2 = p4[2];
        float s = vr0.x + vr0.y + vr0.z + vr0.w + vr1.x + vr1.y + vr1.z + vr1.w
                + vr2.x + vr2.y + vr2.z + vr2.w;
        float ss = vr0.x*vr0.x + vr0.y*vr0.y + vr0.z*vr0.z + vr0.w*vr0.w
                 + vr1.x*vr1.x + vr1.y*vr1.y + vr1.z*vr1.z + vr1.w*vr1.w
                 + vr2.x*vr2.x + vr2.y*vr2.y + vr2.z*vr2.z + vr2.w*vr2.w;
        s  += __shfl_xor(s, 1);  s  += __shfl_xor(s, 2);
        ss += __shfl_xor(ss, 1); ss += __shfl_xor(ss, 2);
        const float mu = s * (1.f / 48.f);
        const float var = ss * (1.f / 48.f) - mu * mu;
        const float rs = rsqrtf(var + 1e-5f);
        float vv[12];
        *reinterpret_cast<float4*>(vv + 0) = vr0;
        *reinterpret_cast<float4*>(vv + 4) = vr1;
        *reinterpret_cast<float4*>(vv + 8) = vr2;
        float ln[12];
        #pragma unroll
        for (int jj = 0; jj < 12; ++jj) {
            const int c = part * 12 + jj;
            ln[jj] = (vv[jj] - mu) * rs * gamma2[c] + beta2[c];
        }
        unsigned short* dst = &aB[t][part * 12];
        #pragma unroll
        for (int jj = 0; jj < 3; ++jj) {
            uint2 u; u.x = pk2(ln[jj*4+0], ln[jj*4+1]); u.y = pk2(ln[jj*4+2], ln[jj*4+3]);
            *reinterpret_cast<uint2*>(dst + jj * 4) = u;
        }
        uint2 z; z.x = 0u; z.y = 0u;                 // zero-pad ch 48..63 (replaces zbuf)
        *reinterpret_cast<uint2*>(&aB[t][48 + part * 4]) = z;
    }
    // no __syncthreads(): LN rows 16w..16w+15 were written by wave w itself.

    const int w = tid >> 6;
    const int l = tid & 63;
    const int m = l & 15;
    const int q = l >> 4;
    const int q4 = q * 4;
    const int tk = w * 16 + m;

    bfrag B0 = *reinterpret_cast<const bfrag*>(&aB[tk][q * 8]);
    bfrag B1 = *reinterpret_cast<const bfrag*>(&aB[tk][32 + q * 8]);   // ch 48..63 are zeros

    f32x4 acc[3];
    acc[0] = (f32x4){0.f, 0.f, 0.f, 0.f};
    acc[1] = (f32x4){0.f, 0.f, 0.f, 0.f};
    acc[2] = (f32x4){0.f, 0.f, 0.f, 0.f};

    // ---- fused GEMM1(+gelu) / exchange / GEMM2 over 6 k-tiles of 32 hidden feats ----
    #pragma unroll 2
    for (int kt = 0; kt < 6; ++kt) {
        uint2 g2[2];
        #pragma unroll
        for (int c2 = 0; c2 < 2; ++c2) {
            const int ct = kt * 2 + c2;
            bfrag A0 = *reinterpret_cast<const bfrag*>(&wsb[WS_W1 + (ct * 16 + m) * 64 + q * 8]);
            bfrag A1 = *reinterpret_cast<const bfrag*>(&wsb[WS_W1 + (ct * 16 + m) * 64 + 32 + q * 8]);
            f32x4 d = {0.f, 0.f, 0.f, 0.f};
            d = __builtin_amdgcn_mfma_f32_16x16x32_bf16(A0, B0, d, 0, 0, 0);
            d = __builtin_amdgcn_mfma_f32_16x16x32_bf16(A1, B1, d, 0, 0, 0);
            const float4 bias = *reinterpret_cast<const float4*>(&fc1_b[ct * 16 + q4]);
            float ge[4];
            #pragma unroll
            for (int i = 0; i < 4; ++i) {
                const float hv = d[i] + (i == 0 ? bias.x : i == 1 ? bias.y : i == 2 ? bias.z : bias.w);
                ge[i] = 0.5f * hv * (1.f + erff(hv * 0.70710678118654752f));
            }
            g2[c2].x = pk2(ge[0], ge[1]);
            g2[c2].y = pk2(ge[2], ge[3]);
        }
        // wave-local 4->8 granularity exchange for this 32-wide k-tile
        const int pp = kt & 1;
        *reinterpret_cast<uint2*>(&sc[w][pp][m][q4])      = g2[0];   // feats q4..q4+3
        *reinterpret_cast<uint2*>(&sc[w][pp][m][16 + q4]) = g2[1];   // feats 16+q4..+3
        bfrag Bh = *reinterpret_cast<const bfrag*>(&sc[w][pp][m][q * 8]);
        #pragma unroll
        for (int ct = 0; ct < 3; ++ct) {
            bfrag Aw = *reinterpret_cast<const bfrag*>(
                &wsb[WS_W2 + (ct * 16 + m) * 192 + kt * 32 + q * 8]);
            acc[ct] = __builtin_amdgcn_mfma_f32_16x16x32_bf16(Aw, Bh, acc[ct], 0, 0, 0);
        }
    }

    // ---- epilogue: D[out_ch][tok] ; float4 RMW residual ----
    {
        const size_t tok = tok0 + tk;
        #pragma unroll
        for (int ct = 0; ct < 3; ++ct) {
            const int c0 = ct * 16 + q4;
            const float4 bias = *reinterpret_cast<const float4*>(&fc2_b[c0]);
            float4* pp = reinterpret_cast<float4*>(xio + tok * 48 + c0);
            float4 r = *pp;
            r.x += acc[ct][0] + bias.x;
            r.y += acc[ct][1] + bias.y;
            r.z += acc[ct][2] + bias.z;
            r.w += acc[ct][3] + bias.w;
            *pp = r;
        }
    }
}

extern "C" void kernel_launch(void* const* d_in, const int* in_sizes, int n_in,
                              void* d_out, int out_size, void* d_ws, size_t ws_size,
                              hipStream_t stream)
{
    (void)in_sizes; (void)n_in; (void)out_size; (void)ws_size;
    const float* x      = (const float*)d_in[0];
    const float* gamma1 = (const float*)d_in[1];
    const float* beta1  = (const float*)d_in[2];
    const float* qkv_w  = (const float*)d_in[3];
    const float* qkv_b  = (const float*)d_in[4];
    const float* rpb_t  = (const float*)d_in[5];
    const float* wf     = (const float*)d_in[6];
    const float* se_w1  = (const float*)d_in[7];
    const float* se_b1  = (const float*)d_in[8];
    const float* se_w2  = (const float*)d_in[9];
    const float* se_b2  = (const float*)d_in[10];
    const float* proj_w = (const float*)d_in[11];
    const float* proj_b = (const float*)d_in[12];
    const float* gamma2 = (const float*)d_in[13];
    const float* beta2  = (const float*)d_in[14];
    const float* fc1_w  = (const float*)d_in[15];
    const float* fc1_b  = (const float*)d_in[16];
    const float* fc2_w  = (const float*)d_in[17];
    const float* fc2_b  = (const float*)d_in[18];
    float* out = (float*)d_out;
    unsigned short* wsb = (unsigned short*)d_ws;

    prep_weights<<<133, 256, 0, stream>>>(fc1_w, fc2_w, qkv_w, qkv_b, proj_w, wsb);
    win_kernel<<<8192, 256, 0, stream>>>(x, gamma1, beta1, wsb, rpb_t, wf,
                                         se_w1, se_b1, se_w2, se_b2, proj_b, out);
    mlp_mfma<<<8192, 256, 0, stream>>>(out, gamma2, beta2, wsb, fc1_b, fc2_b);
}

// Round 2
// 407.671 us; speedup vs baseline: 1.2373x; 1.2326x over previous
//
#include <hip/hip_runtime.h>

// SwinTransformerBlock: B=8, H=W=256, C=48, NH=3, WS=8, SS=4, N=64, HID=192
// fp32 in/out; all GEMMs bf16 MFMA 16x16x32 with "transposed D" (D=[feat][token])
// so epilogues write 4 consecutive features per lane (packed b64 / float4 RMW).

typedef short bfrag __attribute__((ext_vector_type(8)));   // 8 bf16 (4 VGPRs)
typedef float f32x4 __attribute__((ext_vector_type(4)));

__device__ __forceinline__ unsigned cvtpk(float lo, float hi) {
    unsigned r;
    asm("v_cvt_pk_bf16_f32 %0, %1, %2" : "=v"(r) : "v"(lo), "v"(hi));
    return r;   // low16 = bf16(lo), high16 = bf16(hi), RNE
}
__device__ __forceinline__ unsigned short f2bf(float f) {
    return (unsigned short)cvtpk(f, f);
}
__device__ __forceinline__ unsigned pk2(float a, float b) {
    return cvtpk(a, b);
}
__device__ __forceinline__ void bf2x(unsigned u, float& lo, float& hi) {
    union { unsigned i; float f; } a, b;
    a.i = u << 16; b.i = u & 0xffff0000u;
    lo = a.f; hi = b.f;
}

// ---------------- kernel 0: prep bf16 weights in d_ws ----------------
// u16 layout: w1p[192][64] | w2p[48][192] | qkvw[144][64] (q rows x0.25) | projw[48][64]
// then f32 qkvb[144] (q part x0.25)
#define WS_W1   0
#define WS_W2   12288
#define WS_QKVW 21504
#define WS_PROJ 30720
#define WS_QKVB 33792   // f32 from here (u16 offset)
__global__ __launch_bounds__(256) void prep_weights(
    const float* __restrict__ fc1_w, const float* __restrict__ fc2_w,
    const float* __restrict__ qkv_w, const float* __restrict__ qkv_b,
    const float* __restrict__ proj_w,
    unsigned short* __restrict__ ws)
{
    int idx = blockIdx.x * 256 + threadIdx.x;
    if (idx < 12288) {                       // fc1 [192][48] -> [192][64]
        int o = idx >> 6, k = idx & 63;
        ws[WS_W1 + idx] = (k < 48) ? f2bf(fc1_w[o * 48 + k]) : 0;
    } else if (idx < 21504) {                // fc2 [48][192] as-is
        int j = idx - 12288;
        ws[WS_W2 + j] = f2bf(fc2_w[j]);
    } else if (idx < 30720) {                // qkv [144][48] -> [144][64], q x0.25
        int j = idx - 21504;
        int n = j >> 6, k = j & 63;
        float v = (k < 48) ? qkv_w[n * 48 + k] : 0.f;
        if (n < 48) v *= 0.25f;
        ws[WS_QKVW + j] = f2bf(v);
    } else if (idx < 33792) {                // proj [48][48] -> [48][64]
        int j = idx - 30720;
        int n = j >> 6, k = j & 63;
        ws[WS_PROJ + j] = (k < 48) ? f2bf(proj_w[n * 48 + k]) : 0;
    } else if (idx < 33792 + 144) {
        int j = idx - 33792;
        float* bb = reinterpret_cast<float*>(ws + WS_QKVB);
        bb[j] = qkv_b[j] * (j < 48 ? 0.25f : 1.f);
    }
}

// ---------------- kernel 1: per-window block ----------------
__global__ __launch_bounds__(256, 3) void win_kernel(
    const float* __restrict__ x,
    const float* __restrict__ gamma1,
    const float* __restrict__ beta1,
    const unsigned short* __restrict__ wsb,
    const float* __restrict__ rpb_t,
    const float* __restrict__ wf,
    const float* __restrict__ se_w1,
    const float* __restrict__ se_b1,
    const float* __restrict__ se_w2,
    const float* __restrict__ se_b2,
    const float* __restrict__ proj_b,
    float* __restrict__ out)
{
    __shared__ __align__(16) unsigned short xw[64][56];   // LN'd tokens [tok][ch]
    __shared__ __align__(16) unsigned short Qh[64][56];   // [tok][head*16+d]
    __shared__ __align__(16) unsigned short Kh[64][56];
    __shared__ __align__(16) unsigned short ao[64][56];   // attn out + SE [tok][ch]
    __shared__ __align__(16) unsigned short vT[48][72];   // [feat][tok]
    __shared__ __align__(16) unsigned short Pw[4][16][72];// per-wave P [query][key]
    __shared__ __align__(16) unsigned short zbuf[32];     // shared zero fragment
    __shared__ float rpb_s[675];
    __shared__ float se_c[48], se_buf[48];
    __shared__ int   gidx[64];

    const int tid = threadIdx.x;
    const int blk = blockIdx.x;
    const int bb = blk >> 10;
    const int wi = (blk >> 5) & 31;
    const int wj = blk & 31;

    const int w = tid >> 6;       // wave
    const int l = tid & 63;
    const int m = l & 15;
    const int q = l >> 4;
    const int q4 = q * 4;

    for (int i = tid; i < 675; i += 256) rpb_s[i] = rpb_t[i];
    if (tid < 32) zbuf[tid] = 0;

    // ---- LN1 + shifted gather: thread = (token, quarter) ----
    const int t = tid >> 2, part = tid & 3;
    {
        const int ti = t >> 3, tj = t & 7;
        const int si = wi * 8 + ti, sj = wj * 8 + tj;
        const int oi = (si + 4) & 255, oj = (sj + 4) & 255;
        const int g = (bb << 16) + (oi << 8) + oj;
        if (part == 0) gidx[t] = g;
        const float4* p4 = reinterpret_cast<const float4*>(x + (size_t)g * 48 + part * 12);
        float4 vr0 = p4[0], vr1 = p4[1], vr2 = p4[2];
        float s = vr0.x + vr0.y + vr0.z + vr0.w + vr1.x + vr1.y + vr1.z + vr1.w
                + vr2.x + vr2.y + vr2.z + vr2.w;
        float ss = vr0.x*vr0.x + vr0.y*vr0.y + vr0.z*vr0.z + vr0.w*vr0.w
                 + vr1.x*vr1.x + vr1.y*vr1.y + vr1.z*vr1.z + vr1.w*vr1.w
                 + vr2.x*vr2.x + vr2.y*vr2.y + vr2.z*vr2.z + vr2.w*vr2.w;
        s  += __shfl_xor(s, 1);  s  += __shfl_xor(s, 2);
        ss += __shfl_xor(ss, 1); ss += __shfl_xor(ss, 2);
        const float mu = s * (1.f / 48.f);
        const float var = ss * (1.f / 48.f) - mu * mu;
        const float rs = rsqrtf(var + 1e-5f);
        float vv[12];
        *reinterpret_cast<float4*>(vv + 0) = vr0;
        *reinterpret_cast<float4*>(vv + 4) = vr1;
        *reinterpret_cast<float4*>(vv + 8) = vr2;
        float ln[12];
        #pragma unroll
        for (int jj = 0; jj < 12; ++jj) {
            const int c = part * 12 + jj;
            ln[jj] = (vv[jj] - mu) * rs * gamma1[c] + beta1[c];
        }
        unsigned short* dst = &xw[t][part * 12];
        #pragma unroll
        for (int jj = 0; jj < 3; ++jj) {
            uint2 u; u.x = pk2(ln[jj*4+0], ln[jj*4+1]); u.y = pk2(ln[jj*4+2], ln[jj*4+3]);
            *reinterpret_cast<uint2*>(dst + jj * 4) = u;
        }
    }
    __syncthreads();

    // ---- qkv (waves 0-2, 12 tiles each) ; SE stage (wave 3) ----
    if (w < 3) {
        const float* qkvb = reinterpret_cast<const float*>(wsb + WS_QKVB);
        for (int tt = w; tt < 36; tt += 3) {
            const int ct = tt / 4, rt = tt & 3;
            bfrag B0 = *reinterpret_cast<const bfrag*>(&xw[rt * 16 + m][q * 8]);
            bfrag B1 = (q < 2) ? *reinterpret_cast<const bfrag*>(&xw[rt * 16 + m][32 + q * 8])
                               : *reinterpret_cast<const bfrag*>(&zbuf[(q - 2) * 8]);
            bfrag A0 = *reinterpret_cast<const bfrag*>(&wsb[WS_QKVW + (ct * 16 + m) * 64 + q * 8]);
            bfrag A1 = *reinterpret_cast<const bfrag*>(&wsb[WS_QKVW + (ct * 16 + m) * 64 + 32 + q * 8]);
            f32x4 d = {0.f, 0.f, 0.f, 0.f};
            d = __builtin_amdgcn_mfma_f32_16x16x32_bf16(A0, B0, d, 0, 0, 0);
            d = __builtin_amdgcn_mfma_f32_16x16x32_bf16(A1, B1, d, 0, 0, 0);
            const float4 bias = *reinterpret_cast<const float4*>(&qkvb[ct * 16 + q4]);
            float v0 = d[0] + bias.x, v1 = d[1] + bias.y, v2 = d[2] + bias.z, v3 = d[3] + bias.w;
            const int tk = rt * 16 + m;
            if (ct < 3) {
                uint2 u; u.x = pk2(v0, v1); u.y = pk2(v2, v3);
                *reinterpret_cast<uint2*>(&Qh[tk][ct * 16 + q4]) = u;
            } else if (ct < 6) {
                uint2 u; u.x = pk2(v0, v1); u.y = pk2(v2, v3);
                *reinterpret_cast<uint2*>(&Kh[tk][(ct - 3) * 16 + q4]) = u;
            } else {
                float vv4[4] = {v0, v1, v2, v3};
                #pragma unroll
                for (int ii = 0; ii < 4; ++ii) {
                    const int i = (ii + q) & 3;            // rotate rows -> 2-way banks
                    vT[(ct - 6) * 16 + q4 + i][tk] = f2bf(vv4[i]);
                }
            }
        }
    } else if (l < 48) {
        float s = 0.f;
        #pragma unroll 8
        for (int k = 0; k < 64; ++k) {
            union { unsigned i; float f; } u; u.i = ((unsigned)xw[k][l]) << 16;
            s += u.f;
        }
        se_c[l] = s * (1.f / 64.f);
    }
    if (w == 3) {
        __builtin_amdgcn_wave_barrier();
        if (l < 48) {
            float r1[3];
            #pragma unroll
            for (int r = 0; r < 3; ++r) {
                float s = se_b1[r];
                #pragma unroll 8
                for (int c = 0; c < 48; ++c) s += se_c[c] * se_w1[r * 48 + c];
                r1[r] = fmaxf(s, 0.f);
            }
            float s2 = se_b2[l];
            #pragma unroll
            for (int r = 0; r < 3; ++r) s2 += r1[r] * se_w2[l * 3 + r];
            se_buf[l] = wf[0] / (1.f + __expf(-s2));
        }
    }
    __syncthreads();

    // ---- fused attention: 3 slots per wave, no barriers (Pw wave-local) ----
    const bool masked_blk = (wi == 31) || (wj == 31);
    for (int j = 0; j < 3; ++j) {
        const int s = w * 3 + j;
        const int h = s >> 2, rt = s & 3;
        const int tq = rt * 16 + m;                 // query token (= D col)
        const int qi = tq >> 3, qj = tq & 7;
        const int rrq = (wi == 31) ? ((qi >= 4) ? 2 : 1) : 0;
        const int rcq = (wj == 31) ? ((qj >= 4) ? 2 : 1) : 0;
        bfrag Bq = (q < 2) ? *reinterpret_cast<const bfrag*>(&Qh[tq][h * 16 + q * 8])
                           : *reinterpret_cast<const bfrag*>(&zbuf[(q - 2) * 8]);
        float rtot = 0.f;
        #pragma unroll
        for (int ct = 0; ct < 4; ++ct) {
            bfrag Ak = (q < 2) ? *reinterpret_cast<const bfrag*>(&Kh[ct * 16 + m][h * 16 + q * 8])
                               : *reinterpret_cast<const bfrag*>(&zbuf[(q - 2) * 8]);
            f32x4 d = {0.f, 0.f, 0.f, 0.f};
            d = __builtin_amdgcn_mfma_f32_16x16x32_bf16(Ak, Bq, d, 0, 0, 0);
            float pv[4];
            #pragma unroll
            for (int i = 0; i < 4; ++i) {
                const int tk = ct * 16 + q4 + i;    // key token (= D row)
                const int ki = tk >> 3, kj = tk & 7;
                float sc = d[i] + rpb_s[((qi - ki + 7) * 15 + (qj - kj + 7)) * 3 + h];
                if (masked_blk) {
                    const int rrk = (wi == 31) ? ((ki >= 4) ? 2 : 1) : 0;
                    const int rck = (wj == 31) ? ((kj >= 4) ? 2 : 1) : 0;
                    if ((rrk != rrq) || (rck != rcq)) sc -= 100.f;
                }
                const float p = __expf(sc);
                rtot += p;
                pv[i] = p;
            }
            uint2 u; u.x = pk2(pv[0], pv[1]); u.y = pk2(pv[2], pv[3]);
            *reinterpret_cast<uint2*>(&Pw[w][m][ct * 16 + q4]) = u;
        }
        rtot += __shfl_xor(rtot, 16);
        rtot += __shfl_xor(rtot, 32);
        const float rinv = 1.f / rtot;
        // PV: D[vcol][query]
        bfrag Av0 = *reinterpret_cast<const bfrag*>(&vT[h * 16 + m][q * 8]);
        bfrag Av1 = *reinterpret_cast<const bfrag*>(&vT[h * 16 + m][32 + q * 8]);
        bfrag Bp0 = *reinterpret_cast<const bfrag*>(&Pw[w][m][q * 8]);
        bfrag Bp1 = *reinterpret_cast<const bfrag*>(&Pw[w][m][32 + q * 8]);
        f32x4 d = {0.f, 0.f, 0.f, 0.f};
        d = __builtin_amdgcn_mfma_f32_16x16x32_bf16(Av0, Bp0, d, 0, 0, 0);
        d = __builtin_amdgcn_mfma_f32_16x16x32_bf16(Av1, Bp1, d, 0, 0, 0);
        const int c0 = h * 16 + q4;
        const float4 sev = *reinterpret_cast<const float4*>(&se_buf[c0]);
        uint2 xv = *reinterpret_cast<const uint2*>(&xw[tq][c0]);
        float x0, x1, x2, x3;
        bf2x(xv.x, x0, x1); bf2x(xv.y, x2, x3);
        const float o0 = d[0] * rinv + sev.x * x0;
        const float o1 = d[1] * rinv + sev.y * x1;
        const float o2 = d[2] * rinv + sev.z * x2;
        const float o3 = d[3] * rinv + sev.w * x3;
        uint2 u; u.x = pk2(o0, o1); u.y = pk2(o2, o3);
        *reinterpret_cast<uint2*>(&ao[tq][c0]) = u;
    }
    __syncthreads();

    // ---- proj: D[out_ch][token] -> float4 RMW to out (window reverse via gidx) ----
    {
        bfrag B0 = *reinterpret_cast<const bfrag*>(&ao[w * 16 + m][q * 8]);
        bfrag B1 = (q < 2) ? *reinterpret_cast<const bfrag*>(&ao[w * 16 + m][32 + q * 8])
                           : *reinterpret_cast<const bfrag*>(&zbuf[(q - 2) * 8]);
        const int tok = w * 16 + m;
        const int g = gidx[tok];
        #pragma unroll
        for (int ct = 0; ct < 3; ++ct) {
            bfrag A0 = *reinterpret_cast<const bfrag*>(&wsb[WS_PROJ + (ct * 16 + m) * 64 + q * 8]);
            bfrag A1 = *reinterpret_cast<const bfrag*>(&wsb[WS_PROJ + (ct * 16 + m) * 64 + 32 + q * 8]);
            f32x4 d = {0.f, 0.f, 0.f, 0.f};
            d = __builtin_amdgcn_mfma_f32_16x16x32_bf16(A0, B0, d, 0, 0, 0);
            d = __builtin_amdgcn_mfma_f32_16x16x32_bf16(A1, B1, d, 0, 0, 0);
            const int c0 = ct * 16 + q4;
            const float4 bias = *reinterpret_cast<const float4*>(&proj_b[c0]);
            const float4 xr = *reinterpret_cast<const float4*>(&x[(size_t)g * 48 + c0]);
            float4 r;
            r.x = xr.x + d[0] + bias.x;
            r.y = xr.y + d[1] + bias.y;
            r.z = xr.z + d[2] + bias.z;
            r.w = xr.w + d[3] + bias.w;
            *reinterpret_cast<float4*>(&out[(size_t)g * 48 + c0]) = r;
        }
    }
}

// ---------------- kernel 2: MLP v3 — 4 token-tiles per wave, weight loads amortized 4x ----------------
// 256 tokens/block (grid 2048). Wave w owns tokens w*64..w*64+63 = 4 MFMA tiles.
// Per k-tile: A-fragments loaded ONCE, used by 4 independent MFMA+gelu chains (ILP hides
// VMEM/LDS latency in-wave instead of relying on occupancy, which round 1 proved irrelevant).
__global__ __launch_bounds__(256, 3) void mlp_mfma(
    float* __restrict__ xio,
    const float* __restrict__ gamma2,
    const float* __restrict__ beta2,
    const unsigned short* __restrict__ wsb,
    const float* __restrict__ fc1_b,
    const float* __restrict__ fc2_b)
{
    __shared__ __align__(16) unsigned short aB[256][56];     // LN'd [tok][ch] (28.7 KB)
    __shared__ __align__(16) unsigned short sc[4][2][16][40];// per-wave ping-pong exchange (10.2 KB)
    __shared__ __align__(16) unsigned short zbuf[32];
    const int tid = threadIdx.x;
    const size_t tok0 = (size_t)blockIdx.x * 256;

    if (tid < 32) zbuf[tid] = 0;

    // ---- LN2: thread = (token, quarter), 4 rounds of 64 tokens ----
    const int t = tid >> 2, part = tid & 3;
    #pragma unroll
    for (int r = 0; r < 4; ++r) {
        const int tokl = r * 64 + t;
        const float4* p4 = reinterpret_cast<const float4*>(xio + (tok0 + tokl) * 48 + part * 12);
        float4 vr0 = p4[0], vr1 = p4[1], vr2 = p4[2];
        float s = vr0.x + vr0.y + vr0.z + vr0.w + vr1.x + vr1.y + vr1.z + vr1.w
                + vr2.x + vr2.y + vr2.z + vr2.w;
        float ss = vr0.x*vr0.x + vr0.y*vr0.y + vr0.z*vr0.z + vr0.w*vr0.w
                 + vr1.x*vr1.x + vr1.y*vr1.y + vr1.z*vr1.z + vr1.w*vr1.w
                 + vr2.x*vr2.x + vr2.y*vr2.y + vr2.z*vr2.z + vr2.w*vr2.w;
        s  += __shfl_xor(s, 1);  s  += __shfl_xor(s, 2);
        ss += __shfl_xor(ss, 1); ss += __shfl_xor(ss, 2);
        const float mu = s * (1.f / 48.f);
        const float var = ss * (1.f / 48.f) - mu * mu;
        const float rs = rsqrtf(var + 1e-5f);
        float vv[12];
        *reinterpret_cast<float4*>(vv + 0) = vr0;
        *reinterpret_cast<float4*>(vv + 4) = vr1;
        *reinterpret_cast<float4*>(vv + 8) = vr2;
        float ln[12];
        #pragma unroll
        for (int jj = 0; jj < 12; ++jj) {
            const int c = part * 12 + jj;
            ln[jj] = (vv[jj] - mu) * rs * gamma2[c] + beta2[c];
        }
        unsigned short* dst = &aB[tokl][part * 12];
        #pragma unroll
        for (int jj = 0; jj < 3; ++jj) {
            uint2 u; u.x = pk2(ln[jj*4+0], ln[jj*4+1]); u.y = pk2(ln[jj*4+2], ln[jj*4+3]);
            *reinterpret_cast<uint2*>(dst + jj * 4) = u;
        }
    }
    __syncthreads();

    const int w = tid >> 6;
    const int l = tid & 63;
    const int m = l & 15;
    const int q = l >> 4;
    const int q4 = q * 4;
    const int base = w * 64;                 // wave's token base within block

    // B fragments for the wave's 4 token-tiles
    bfrag B0[4], B1[4];
    #pragma unroll
    for (int T = 0; T < 4; ++T) {
        B0[T] = *reinterpret_cast<const bfrag*>(&aB[base + T * 16 + m][q * 8]);
        B1[T] = (q < 2) ? *reinterpret_cast<const bfrag*>(&aB[base + T * 16 + m][32 + q * 8])
                        : *reinterpret_cast<const bfrag*>(&zbuf[(q - 2) * 8]);
    }

    f32x4 acc[4][3];
    #pragma unroll
    for (int T = 0; T < 4; ++T)
        #pragma unroll
        for (int ct = 0; ct < 3; ++ct) acc[T][ct] = (f32x4){0.f, 0.f, 0.f, 0.f};

    // ---- fused GEMM1(+gelu) / exchange / GEMM2 over 6 k-tiles of 32 hidden feats ----
    #pragma unroll 2
    for (int kt = 0; kt < 6; ++kt) {
        uint2 g2[4][2];                       // packed gelu output per (tile, c2)
        #pragma unroll
        for (int c2 = 0; c2 < 2; ++c2) {
            const int ct = kt * 2 + c2;
            bfrag A0 = *reinterpret_cast<const bfrag*>(&wsb[WS_W1 + (ct * 16 + m) * 64 + q * 8]);
            bfrag A1 = *reinterpret_cast<const bfrag*>(&wsb[WS_W1 + (ct * 16 + m) * 64 + 32 + q * 8]);
            const float4 bias = *reinterpret_cast<const float4*>(&fc1_b[ct * 16 + q4]);
            #pragma unroll
            for (int T = 0; T < 4; ++T) {
                f32x4 d = {0.f, 0.f, 0.f, 0.f};
                d = __builtin_amdgcn_mfma_f32_16x16x32_bf16(A0, B0[T], d, 0, 0, 0);
                d = __builtin_amdgcn_mfma_f32_16x16x32_bf16(A1, B1[T], d, 0, 0, 0);
                float ge[4];
                #pragma unroll
                for (int i = 0; i < 4; ++i) {
                    const float hv = d[i] + (i == 0 ? bias.x : i == 1 ? bias.y : i == 2 ? bias.z : bias.w);
                    ge[i] = 0.5f * hv * (1.f + erff(hv * 0.70710678118654752f));
                }
                g2[T][c2].x = pk2(ge[0], ge[1]);
                g2[T][c2].y = pk2(ge[2], ge[3]);
            }
        }
        // shared GEMM2 weight fragments for this k-tile (loaded once, used by 4 tiles)
        bfrag Aw[3];
        #pragma unroll
        for (int ct = 0; ct < 3; ++ct)
            Aw[ct] = *reinterpret_cast<const bfrag*>(
                &wsb[WS_W2 + (ct * 16 + m) * 192 + kt * 32 + q * 8]);
        // per tile: 4->8 granularity exchange (2-buffer ping-pong, wave-local, in-order DS)
        #pragma unroll
        for (int T = 0; T < 4; ++T) {
            const int pp = T & 1;
            *reinterpret_cast<uint2*>(&sc[w][pp][m][q4])      = g2[T][0];   // feats q4..q4+3
            *reinterpret_cast<uint2*>(&sc[w][pp][m][16 + q4]) = g2[T][1];   // feats 16+q4..+3
            bfrag Bh = *reinterpret_cast<const bfrag*>(&sc[w][pp][m][q * 8]);
            #pragma unroll
            for (int ct = 0; ct < 3; ++ct)
                acc[T][ct] = __builtin_amdgcn_mfma_f32_16x16x32_bf16(Aw[ct], Bh, acc[T][ct], 0, 0, 0);
        }
    }

    // ---- epilogue: D[out_ch][tok] ; float4 RMW residual ----
    #pragma unroll
    for (int T = 0; T < 4; ++T) {
        const size_t tok = tok0 + base + T * 16 + m;
        #pragma unroll
        for (int ct = 0; ct < 3; ++ct) {
            const int c0 = ct * 16 + q4;
            const float4 bias = *reinterpret_cast<const float4*>(&fc2_b[c0]);
            float4* pp = reinterpret_cast<float4*>(xio + tok * 48 + c0);
            float4 r = *pp;
            r.x += acc[T][ct][0] + bias.x;
            r.y += acc[T][ct][1] + bias.y;
            r.z += acc[T][ct][2] + bias.z;
            r.w += acc[T][ct][3] + bias.w;
            *pp = r;
        }
    }
}

extern "C" void kernel_launch(void* const* d_in, const int* in_sizes, int n_in,
                              void* d_out, int out_size, void* d_ws, size_t ws_size,
                              hipStream_t stream)
{
    (void)in_sizes; (void)n_in; (void)out_size; (void)ws_size;
    const float* x      = (const float*)d_in[0];
    const float* gamma1 = (const float*)d_in[1];
    const float* beta1  = (const float*)d_in[2];
    const float* qkv_w  = (const float*)d_in[3];
    const float* qkv_b  = (const float*)d_in[4];
    const float* rpb_t  = (const float*)d_in[5];
    const float* wf     = (const float*)d_in[6];
    const float* se_w1  = (const float*)d_in[7];
    const float* se_b1  = (const float*)d_in[8];
    const float* se_w2  = (const float*)d_in[9];
    const float* se_b2  = (const float*)d_in[10];
    const float* proj_w = (const float*)d_in[11];
    const float* proj_b = (const float*)d_in[12];
    const float* gamma2 = (const float*)d_in[13];
    const float* beta2  = (const float*)d_in[14];
    const float* fc1_w  = (const float*)d_in[15];
    const float* fc1_b  = (const float*)d_in[16];
    const float* fc2_w  = (const float*)d_in[17];
    const float* fc2_b  = (const float*)d_in[18];
    float* out = (float*)d_out;
    unsigned short* wsb = (unsigned short*)d_ws;

    prep_weights<<<133, 256, 0, stream>>>(fc1_w, fc2_w, qkv_w, qkv_b, proj_w, wsb);
    win_kernel<<<8192, 256, 0, stream>>>(x, gamma1, beta1, wsb, rpb_t, wf,
                                         se_w1, se_b1, se_w2, se_b2, proj_b, out);
    mlp_mfma<<<2048, 256, 0, stream>>>(out, gamma2, beta2, wsb, fc1_b, fc2_b);
}

// Round 6
// 359.039 us; speedup vs baseline: 1.4049x; 1.1354x over previous
//
#include <hip/hip_runtime.h>

// SwinTransformerBlock: B=8, H=W=256, C=48, NH=3, WS=8, SS=4, N=64, HID=192
// fp32 in/out; all GEMMs bf16 MFMA 16x16x32 with "transposed D" (D=[feat][token])
// so epilogues write 4 consecutive features per lane (packed b64 / float4 RMW).

typedef short bfrag __attribute__((ext_vector_type(8)));   // 8 bf16 (4 VGPRs)
typedef float f32x4 __attribute__((ext_vector_type(4)));

__device__ __forceinline__ unsigned cvtpk(float lo, float hi) {
    unsigned r;
    asm("v_cvt_pk_bf16_f32 %0, %1, %2" : "=v"(r) : "v"(lo), "v"(hi));
    return r;   // low16 = bf16(lo), high16 = bf16(hi), RNE
}
__device__ __forceinline__ unsigned short f2bf(float f) {
    return (unsigned short)cvtpk(f, f);
}
__device__ __forceinline__ unsigned pk2(float a, float b) {
    return cvtpk(a, b);
}
__device__ __forceinline__ void bf2x(unsigned u, float& lo, float& hi) {
    union { unsigned i; float f; } a, b;
    a.i = u << 16; b.i = u & 0xffff0000u;
    lo = a.f; hi = b.f;
}

// ---------------- kernel 0: prep bf16 weights in d_ws ----------------
// u16 layout: w1p[192][64] | w2p[48][192] | qkvw[144][64] (q rows x0.25) | projw[48][64]
// then f32 qkvb[144] (q part x0.25)
#define WS_W1   0
#define WS_W2   12288
#define WS_QKVW 21504
#define WS_PROJ 30720
#define WS_QKVB 33792   // f32 from here (u16 offset)
__global__ __launch_bounds__(256) void prep_weights(
    const float* __restrict__ fc1_w, const float* __restrict__ fc2_w,
    const float* __restrict__ qkv_w, const float* __restrict__ qkv_b,
    const float* __restrict__ proj_w,
    unsigned short* __restrict__ ws)
{
    int idx = blockIdx.x * 256 + threadIdx.x;
    if (idx < 12288) {                       // fc1 [192][48] -> [192][64]
        int o = idx >> 6, k = idx & 63;
        ws[WS_W1 + idx] = (k < 48) ? f2bf(fc1_w[o * 48 + k]) : 0;
    } else if (idx < 21504) {                // fc2 [48][192] as-is
        int j = idx - 12288;
        ws[WS_W2 + j] = f2bf(fc2_w[j]);
    } else if (idx < 30720) {                // qkv [144][48] -> [144][64], q x0.25
        int j = idx - 21504;
        int n = j >> 6, k = j & 63;
        float v = (k < 48) ? qkv_w[n * 48 + k] : 0.f;
        if (n < 48) v *= 0.25f;
        ws[WS_QKVW + j] = f2bf(v);
    } else if (idx < 33792) {                // proj [48][48] -> [48][64]
        int j = idx - 30720;
        int n = j >> 6, k = j & 63;
        ws[WS_PROJ + j] = (k < 48) ? f2bf(proj_w[n * 48 + k]) : 0;
    } else if (idx < 33792 + 144) {
        int j = idx - 33792;
        float* bb = reinterpret_cast<float*>(ws + WS_QKVB);
        bb[j] = qkv_b[j] * (j < 48 ? 0.25f : 1.f);
    }
}

// ---------------- kernel 1: per-window block (v5: r2 attention/proj + QKV remap + proj-load hoist) ----------------
// BISECTION BUILD: attention phase, barrier 3, and proj structure are the r2-PROVEN text
// verbatim. Only two low-risk changes kept from the r3 restructure:
//  (1) QKV: wave w owns feature tiles ct=3w..3w+2, A-frags+bias hoisted (1 VMEM wait vs 12).
//  (2) proj A-frags + x residual loaded (global->reg, no LDS semantics) before attention.
__global__ __launch_bounds__(256, 3) void win_kernel(
    const float* __restrict__ x,
    const float* __restrict__ gamma1,
    const float* __restrict__ beta1,
    const unsigned short* __restrict__ wsb,
    const float* __restrict__ rpb_t,
    const float* __restrict__ wf,
    const float* __restrict__ se_w1,
    const float* __restrict__ se_b1,
    const float* __restrict__ se_w2,
    const float* __restrict__ se_b2,
    const float* __restrict__ proj_b,
    float* __restrict__ out)
{
    __shared__ __align__(16) unsigned short xw[64][56];   // LN'd tokens [tok][ch]
    __shared__ __align__(16) unsigned short Qh[64][56];   // [tok][head*16+d]
    __shared__ __align__(16) unsigned short Kh[64][56];
    __shared__ __align__(16) unsigned short ao[64][56];   // attn out + SE [tok][ch]
    __shared__ __align__(16) unsigned short vT[48][72];   // [feat][tok]
    __shared__ __align__(16) unsigned short Pw[4][16][72];// per-wave P [query][key]
    __shared__ __align__(16) unsigned short zbuf[32];     // shared zero fragment
    __shared__ float rpb_s[675];
    __shared__ float se_c[48], se_buf[48];
    __shared__ int   gidx[64];

    const int tid = threadIdx.x;
    const int blk = blockIdx.x;
    const int bb = blk >> 10;
    const int wi = (blk >> 5) & 31;
    const int wj = blk & 31;

    const int w = tid >> 6;       // wave
    const int l = tid & 63;
    const int m = l & 15;
    const int q = l >> 4;
    const int q4 = q * 4;

    for (int i = tid; i < 675; i += 256) rpb_s[i] = rpb_t[i];
    if (tid < 32) zbuf[tid] = 0;

    // ---- LN1 + shifted gather: thread = (token, quarter) ----
    const int t = tid >> 2, part = tid & 3;
    {
        const int ti = t >> 3, tj = t & 7;
        const int si = wi * 8 + ti, sj = wj * 8 + tj;
        const int oi = (si + 4) & 255, oj = (sj + 4) & 255;
        const int g = (bb << 16) + (oi << 8) + oj;
        if (part == 0) gidx[t] = g;
        const float4* p4 = reinterpret_cast<const float4*>(x + (size_t)g * 48 + part * 12);
        float4 vr0 = p4[0], vr1 = p4[1], vr2 = p4[2];
        float s = vr0.x + vr0.y + vr0.z + vr0.w + vr1.x + vr1.y + vr1.z + vr1.w
                + vr2.x + vr2.y + vr2.z + vr2.w;
        float ss = vr0.x*vr0.x + vr0.y*vr0.y + vr0.z*vr0.z + vr0.w*vr0.w
                 + vr1.x*vr1.x + vr1.y*vr1.y + vr1.z*vr1.z + vr1.w*vr1.w
                 + vr2.x*vr2.x + vr2.y*vr2.y + vr2.z*vr2.z + vr2.w*vr2.w;
        s  += __shfl_xor(s, 1);  s  += __shfl_xor(s, 2);
        ss += __shfl_xor(ss, 1); ss += __shfl_xor(ss, 2);
        const float mu = s * (1.f / 48.f);
        const float var = ss * (1.f / 48.f) - mu * mu;
        const float rs = rsqrtf(var + 1e-5f);
        float vv[12];
        *reinterpret_cast<float4*>(vv + 0) = vr0;
        *reinterpret_cast<float4*>(vv + 4) = vr1;
        *reinterpret_cast<float4*>(vv + 8) = vr2;
        float ln[12];
        #pragma unroll
        for (int jj = 0; jj < 12; ++jj) {
            const int c = part * 12 + jj;
            ln[jj] = (vv[jj] - mu) * rs * gamma1[c] + beta1[c];
        }
        unsigned short* dst = &xw[t][part * 12];
        #pragma unroll
        for (int jj = 0; jj < 3; ++jj) {
            uint2 u; u.x = pk2(ln[jj*4+0], ln[jj*4+1]); u.y = pk2(ln[jj*4+2], ln[jj*4+3]);
            *reinterpret_cast<uint2*>(dst + jj * 4) = u;
        }
    }
    __syncthreads();

    // ---- qkv (wave w owns ct = 3w..3w+2; A-frags/bias hoisted) ; SE (wave 3) ----
    if (w < 3) {
        const float* qkvb = reinterpret_cast<const float*>(wsb + WS_QKVB);
        bfrag A0[3], A1[3];
        float4 bias[3];
        #pragma unroll
        for (int cc = 0; cc < 3; ++cc) {
            const int ct = w * 3 + cc;
            A0[cc] = *reinterpret_cast<const bfrag*>(&wsb[WS_QKVW + (ct * 16 + m) * 64 + q * 8]);
            A1[cc] = *reinterpret_cast<const bfrag*>(&wsb[WS_QKVW + (ct * 16 + m) * 64 + 32 + q * 8]);
            bias[cc] = *reinterpret_cast<const float4*>(&qkvb[ct * 16 + q4]);
        }
        #pragma unroll
        for (int rt = 0; rt < 4; ++rt) {
            const int tk = rt * 16 + m;
            bfrag B0 = *reinterpret_cast<const bfrag*>(&xw[tk][q * 8]);
            bfrag B1 = (q < 2) ? *reinterpret_cast<const bfrag*>(&xw[tk][32 + q * 8])
                               : *reinterpret_cast<const bfrag*>(&zbuf[(q - 2) * 8]);
            #pragma unroll
            for (int cc = 0; cc < 3; ++cc) {
                f32x4 d = {0.f, 0.f, 0.f, 0.f};
                d = __builtin_amdgcn_mfma_f32_16x16x32_bf16(A0[cc], B0, d, 0, 0, 0);
                d = __builtin_amdgcn_mfma_f32_16x16x32_bf16(A1[cc], B1, d, 0, 0, 0);
                float v0 = d[0] + bias[cc].x, v1 = d[1] + bias[cc].y;
                float v2 = d[2] + bias[cc].z, v3 = d[3] + bias[cc].w;
                if (w == 0) {
                    uint2 u; u.x = pk2(v0, v1); u.y = pk2(v2, v3);
                    *reinterpret_cast<uint2*>(&Qh[tk][cc * 16 + q4]) = u;
                } else if (w == 1) {
                    uint2 u; u.x = pk2(v0, v1); u.y = pk2(v2, v3);
                    *reinterpret_cast<uint2*>(&Kh[tk][cc * 16 + q4]) = u;
                } else {
                    float vv4[4] = {v0, v1, v2, v3};
                    #pragma unroll
                    for (int ii = 0; ii < 4; ++ii) {
                        const int i = (ii + q) & 3;        // rotate rows -> 2-way banks
                        vT[cc * 16 + q4 + i][tk] = f2bf(vv4[i]);
                    }
                }
            }
        }
    } else if (l < 48) {
        float s = 0.f;
        #pragma unroll 8
        for (int k = 0; k < 64; ++k) {
            union { unsigned i; float f; } u; u.i = ((unsigned)xw[k][l]) << 16;
            s += u.f;
        }
        se_c[l] = s * (1.f / 64.f);
    }
    if (w == 3) {
        __builtin_amdgcn_wave_barrier();
        if (l < 48) {
            float r1[3];
            #pragma unroll
            for (int r = 0; r < 3; ++r) {
                float s = se_b1[r];
                #pragma unroll 8
                for (int c = 0; c < 48; ++c) s += se_c[c] * se_w1[r * 48 + c];
                r1[r] = fmaxf(s, 0.f);
            }
            float s2 = se_b2[l];
            #pragma unroll
            for (int r = 0; r < 3; ++r) s2 += r1[r] * se_w2[l * 3 + r];
            se_buf[l] = wf[0] / (1.f + __expf(-s2));
        }
    }
    __syncthreads();

    // ---- hoist proj A-frags + x residual (GLOBAL loads only; consumed after barrier 3) ----
    const int ptok = w * 16 + m;                 // this wave's proj token row
    const int pg = gidx[ptok];
    bfrag PA0[3], PA1[3];
    float4 xres[3];
    #pragma unroll
    for (int ct = 0; ct < 3; ++ct) {
        PA0[ct] = *reinterpret_cast<const bfrag*>(&wsb[WS_PROJ + (ct * 16 + m) * 64 + q * 8]);
        PA1[ct] = *reinterpret_cast<const bfrag*>(&wsb[WS_PROJ + (ct * 16 + m) * 64 + 32 + q * 8]);
        xres[ct] = *reinterpret_cast<const float4*>(&x[(size_t)pg * 48 + ct * 16 + q4]);
    }

    // ---- fused attention: 3 slots per wave, r2-PROVEN structure (verbatim) ----
    const bool masked_blk = (wi == 31) || (wj == 31);
    for (int j = 0; j < 3; ++j) {
        const int s = w * 3 + j;
        const int h = s >> 2, rt = s & 3;
        const int tq = rt * 16 + m;                 // query token (= D col)
        const int qi = tq >> 3, qj = tq & 7;
        const int rrq = (wi == 31) ? ((qi >= 4) ? 2 : 1) : 0;
        const int rcq = (wj == 31) ? ((qj >= 4) ? 2 : 1) : 0;
        bfrag Bq = (q < 2) ? *reinterpret_cast<const bfrag*>(&Qh[tq][h * 16 + q * 8])
                           : *reinterpret_cast<const bfrag*>(&zbuf[(q - 2) * 8]);
        float rtot = 0.f;
        #pragma unroll
        for (int ct = 0; ct < 4; ++ct) {
            bfrag Ak = (q < 2) ? *reinterpret_cast<const bfrag*>(&Kh[ct * 16 + m][h * 16 + q * 8])
                               : *reinterpret_cast<const bfrag*>(&zbuf[(q - 2) * 8]);
            f32x4 d = {0.f, 0.f, 0.f, 0.f};
            d = __builtin_amdgcn_mfma_f32_16x16x32_bf16(Ak, Bq, d, 0, 0, 0);
            float pv[4];
            #pragma unroll
            for (int i = 0; i < 4; ++i) {
                const int tk = ct * 16 + q4 + i;    // key token (= D row)
                const int ki = tk >> 3, kj = tk & 7;
                float sc = d[i] + rpb_s[((qi - ki + 7) * 15 + (qj - kj + 7)) * 3 + h];
                if (masked_blk) {
                    const int rrk = (wi == 31) ? ((ki >= 4) ? 2 : 1) : 0;
                    const int rck = (wj == 31) ? ((kj >= 4) ? 2 : 1) : 0;
                    if ((rrk != rrq) || (rck != rcq)) sc -= 100.f;
                }
                const float p = __expf(sc);
                rtot += p;
                pv[i] = p;
            }
            uint2 u; u.x = pk2(pv[0], pv[1]); u.y = pk2(pv[2], pv[3]);
            *reinterpret_cast<uint2*>(&Pw[w][m][ct * 16 + q4]) = u;
        }
        rtot += __shfl_xor(rtot, 16);
        rtot += __shfl_xor(rtot, 32);
        const float rinv = 1.f / rtot;
        // PV: D[vcol][query]
        bfrag Av0 = *reinterpret_cast<const bfrag*>(&vT[h * 16 + m][q * 8]);
        bfrag Av1 = *reinterpret_cast<const bfrag*>(&vT[h * 16 + m][32 + q * 8]);
        bfrag Bp0 = *reinterpret_cast<const bfrag*>(&Pw[w][m][q * 8]);
        bfrag Bp1 = *reinterpret_cast<const bfrag*>(&Pw[w][m][32 + q * 8]);
        f32x4 d = {0.f, 0.f, 0.f, 0.f};
        d = __builtin_amdgcn_mfma_f32_16x16x32_bf16(Av0, Bp0, d, 0, 0, 0);
        d = __builtin_amdgcn_mfma_f32_16x16x32_bf16(Av1, Bp1, d, 0, 0, 0);
        const int c0 = h * 16 + q4;
        const float4 sev = *reinterpret_cast<const float4*>(&se_buf[c0]);
        uint2 xv = *reinterpret_cast<const uint2*>(&xw[tq][c0]);
        float x0, x1, x2, x3;
        bf2x(xv.x, x0, x1); bf2x(xv.y, x2, x3);
        const float o0 = d[0] * rinv + sev.x * x0;
        const float o1 = d[1] * rinv + sev.y * x1;
        const float o2 = d[2] * rinv + sev.z * x2;
        const float o3 = d[3] * rinv + sev.w * x3;
        uint2 u; u.x = pk2(o0, o1); u.y = pk2(o2, o3);
        *reinterpret_cast<uint2*>(&ao[tq][c0]) = u;
    }
    __syncthreads();

    // ---- proj: D[out_ch][token] -> float4 RMW to out (r2 structure, hoisted operands) ----
    {
        bfrag B0 = *reinterpret_cast<const bfrag*>(&ao[ptok][q * 8]);
        bfrag B1 = (q < 2) ? *reinterpret_cast<const bfrag*>(&ao[ptok][32 + q * 8])
                           : *reinterpret_cast<const bfrag*>(&zbuf[(q - 2) * 8]);
        #pragma unroll
        for (int ct = 0; ct < 3; ++ct) {
            f32x4 d = {0.f, 0.f, 0.f, 0.f};
            d = __builtin_amdgcn_mfma_f32_16x16x32_bf16(PA0[ct], B0, d, 0, 0, 0);
            d = __builtin_amdgcn_mfma_f32_16x16x32_bf16(PA1[ct], B1, d, 0, 0, 0);
            const int c0 = ct * 16 + q4;
            const float4 bias = *reinterpret_cast<const float4*>(&proj_b[c0]);
            float4 r;
            r.x = xres[ct].x + d[0] + bias.x;
            r.y = xres[ct].y + d[1] + bias.y;
            r.z = xres[ct].z + d[2] + bias.z;
            r.w = xres[ct].w + d[3] + bias.w;
            *reinterpret_cast<float4*>(&out[(size_t)pg * 48 + c0]) = r;
        }
    }
}

// ---------------- kernel 2: MLP v3 — 4 token-tiles per wave, weight loads amortized 4x ----------------
// 256 tokens/block (grid 2048). Wave w owns tokens w*64..w*64+63 = 4 MFMA tiles.
// Per k-tile: A-fragments loaded ONCE, used by 4 independent MFMA+gelu chains (ILP hides
// VMEM/LDS latency in-wave instead of relying on occupancy, which round 1 proved irrelevant).
// UNCHANGED from the round-2 passing version.
__global__ __launch_bounds__(256, 3) void mlp_mfma(
    float* __restrict__ xio,
    const float* __restrict__ gamma2,
    const float* __restrict__ beta2,
    const unsigned short* __restrict__ wsb,
    const float* __restrict__ fc1_b,
    const float* __restrict__ fc2_b)
{
    __shared__ __align__(16) unsigned short aB[256][56];     // LN'd [tok][ch] (28.7 KB)
    __shared__ __align__(16) unsigned short sc[4][2][16][40];// per-wave ping-pong exchange (10.2 KB)
    __shared__ __align__(16) unsigned short zbuf[32];
    const int tid = threadIdx.x;
    const size_t tok0 = (size_t)blockIdx.x * 256;

    if (tid < 32) zbuf[tid] = 0;

    // ---- LN2: thread = (token, quarter), 4 rounds of 64 tokens ----
    const int t = tid >> 2, part = tid & 3;
    #pragma unroll
    for (int r = 0; r < 4; ++r) {
        const int tokl = r * 64 + t;
        const float4* p4 = reinterpret_cast<const float4*>(xio + (tok0 + tokl) * 48 + part * 12);
        float4 vr0 = p4[0], vr1 = p4[1], vr2 = p4[2];
        float s = vr0.x + vr0.y + vr0.z + vr0.w + vr1.x + vr1.y + vr1.z + vr1.w
                + vr2.x + vr2.y + vr2.z + vr2.w;
        float ss = vr0.x*vr0.x + vr0.y*vr0.y + vr0.z*vr0.z + vr0.w*vr0.w
                 + vr1.x*vr1.x + vr1.y*vr1.y + vr1.z*vr1.z + vr1.w*vr1.w
                 + vr2.x*vr2.x + vr2.y*vr2.y + vr2.z*vr2.z + vr2.w*vr2.w;
        s  += __shfl_xor(s, 1);  s  += __shfl_xor(s, 2);
        ss += __shfl_xor(ss, 1); ss += __shfl_xor(ss, 2);
        const float mu = s * (1.f / 48.f);
        const float var = ss * (1.f / 48.f) - mu * mu;
        const float rs = rsqrtf(var + 1e-5f);
        float vv[12];
        *reinterpret_cast<float4*>(vv + 0) = vr0;
        *reinterpret_cast<float4*>(vv + 4) = vr1;
        *reinterpret_cast<float4*>(vv + 8) = vr2;
        float ln[12];
        #pragma unroll
        for (int jj = 0; jj < 12; ++jj) {
            const int c = part * 12 + jj;
            ln[jj] = (vv[jj] - mu) * rs * gamma2[c] + beta2[c];
        }
        unsigned short* dst = &aB[tokl][part * 12];
        #pragma unroll
        for (int jj = 0; jj < 3; ++jj) {
            uint2 u; u.x = pk2(ln[jj*4+0], ln[jj*4+1]); u.y = pk2(ln[jj*4+2], ln[jj*4+3]);
            *reinterpret_cast<uint2*>(dst + jj * 4) = u;
        }
    }
    __syncthreads();

    const int w = tid >> 6;
    const int l = tid & 63;
    const int m = l & 15;
    const int q = l >> 4;
    const int q4 = q * 4;
    const int base = w * 64;                 // wave's token base within block

    // B fragments for the wave's 4 token-tiles
    bfrag B0[4], B1[4];
    #pragma unroll
    for (int T = 0; T < 4; ++T) {
        B0[T] = *reinterpret_cast<const bfrag*>(&aB[base + T * 16 + m][q * 8]);
        B1[T] = (q < 2) ? *reinterpret_cast<const bfrag*>(&aB[base + T * 16 + m][32 + q * 8])
                        : *reinterpret_cast<const bfrag*>(&zbuf[(q - 2) * 8]);
    }

    f32x4 acc[4][3];
    #pragma unroll
    for (int T = 0; T < 4; ++T)
        #pragma unroll
        for (int ct = 0; ct < 3; ++ct) acc[T][ct] = (f32x4){0.f, 0.f, 0.f, 0.f};

    // ---- fused GEMM1(+gelu) / exchange / GEMM2 over 6 k-tiles of 32 hidden feats ----
    #pragma unroll 2
    for (int kt = 0; kt < 6; ++kt) {
        uint2 g2[4][2];                       // packed gelu output per (tile, c2)
        #pragma unroll
        for (int c2 = 0; c2 < 2; ++c2) {
            const int ct = kt * 2 + c2;
            bfrag A0 = *reinterpret_cast<const bfrag*>(&wsb[WS_W1 + (ct * 16 + m) * 64 + q * 8]);
            bfrag A1 = *reinterpret_cast<const bfrag*>(&wsb[WS_W1 + (ct * 16 + m) * 64 + 32 + q * 8]);
            const float4 bias = *reinterpret_cast<const float4*>(&fc1_b[ct * 16 + q4]);
            #pragma unroll
            for (int T = 0; T < 4; ++T) {
                f32x4 d = {0.f, 0.f, 0.f, 0.f};
                d = __builtin_amdgcn_mfma_f32_16x16x32_bf16(A0, B0[T], d, 0, 0, 0);
                d = __builtin_amdgcn_mfma_f32_16x16x32_bf16(A1, B1[T], d, 0, 0, 0);
                float ge[4];
                #pragma unroll
                for (int i = 0; i < 4; ++i) {
                    const float hv = d[i] + (i == 0 ? bias.x : i == 1 ? bias.y : i == 2 ? bias.z : bias.w);
                    ge[i] = 0.5f * hv * (1.f + erff(hv * 0.70710678118654752f));
                }
                g2[T][c2].x = pk2(ge[0], ge[1]);
                g2[T][c2].y = pk2(ge[2], ge[3]);
            }
        }
        // shared GEMM2 weight fragments for this k-tile (loaded once, used by 4 tiles)
        bfrag Aw[3];
        #pragma unroll
        for (int ct = 0; ct < 3; ++ct)
            Aw[ct] = *reinterpret_cast<const bfrag*>(
                &wsb[WS_W2 + (ct * 16 + m) * 192 + kt * 32 + q * 8]);
        // per tile: 4->8 granularity exchange (2-buffer ping-pong, wave-local, in-order DS)
        #pragma unroll
        for (int T = 0; T < 4; ++T) {
            const int pp = T & 1;
            *reinterpret_cast<uint2*>(&sc[w][pp][m][q4])      = g2[T][0];   // feats q4..q4+3
            *reinterpret_cast<uint2*>(&sc[w][pp][m][16 + q4]) = g2[T][1];   // feats 16+q4..+3
            bfrag Bh = *reinterpret_cast<const bfrag*>(&sc[w][pp][m][q * 8]);
            #pragma unroll
            for (int ct = 0; ct < 3; ++ct)
                acc[T][ct] = __builtin_amdgcn_mfma_f32_16x16x32_bf16(Aw[ct], Bh, acc[T][ct], 0, 0, 0);
        }
    }

    // ---- epilogue: D[out_ch][tok] ; float4 RMW residual ----
    #pragma unroll
    for (int T = 0; T < 4; ++T) {
        const size_t tok = tok0 + base + T * 16 + m;
        #pragma unroll
        for (int ct = 0; ct < 3; ++ct) {
            const int c0 = ct * 16 + q4;
            const float4 bias = *reinterpret_cast<const float4*>(&fc2_b[c0]);
            float4* pp = reinterpret_cast<float4*>(xio + tok * 48 + c0);
            float4 r = *pp;
            r.x += acc[T][ct][0] + bias.x;
            r.y += acc[T][ct][1] + bias.y;
            r.z += acc[T][ct][2] + bias.z;
            r.w += acc[T][ct][3] + bias.w;
            *pp = r;
        }
    }
}

extern "C" void kernel_launch(void* const* d_in, const int* in_sizes, int n_in,
                              void* d_out, int out_size, void* d_ws, size_t ws_size,
                              hipStream_t stream)
{
    (void)in_sizes; (void)n_in; (void)out_size; (void)ws_size;
    const float* x      = (const float*)d_in[0];
    const float* gamma1 = (const float*)d_in[1];
    const float* beta1  = (const float*)d_in[2];
    const float* qkv_w  = (const float*)d_in[3];
    const float* qkv_b  = (const float*)d_in[4];
    const float* rpb_t  = (const float*)d_in[5];
    const float* wf     = (const float*)d_in[6];
    const float* se_w1  = (const float*)d_in[7];
    const float* se_b1  = (const float*)d_in[8];
    const float* se_w2  = (const float*)d_in[9];
    const float* se_b2  = (const float*)d_in[10];
    const float* proj_w = (const float*)d_in[11];
    const float* proj_b = (const float*)d_in[12];
    const float* gamma2 = (const float*)d_in[13];
    const float* beta2  = (const float*)d_in[14];
    const float* fc1_w  = (const float*)d_in[15];
    const float* fc1_b  = (const float*)d_in[16];
    const float* fc2_w  = (const float*)d_in[17];
    const float* fc2_b  = (const float*)d_in[18];
    float* out = (float*)d_out;
    unsigned short* wsb = (unsigned short*)d_ws;

    prep_weights<<<133, 256, 0, stream>>>(fc1_w, fc2_w, qkv_w, qkv_b, proj_w, wsb);
    win_kernel<<<8192, 256, 0, stream>>>(x, gamma1, beta1, wsb, rpb_t, wf,
                                         se_w1, se_b1, se_w2, se_b2, proj_b, out);
    mlp_mfma<<<2048, 256, 0, stream>>>(out, gamma2, beta2, wsb, fc1_b, fc2_b);
}